// Round 16
// baseline (1811.699 us; speedup 1.0000x reference)
//
#include <hip/hip_runtime.h>

// ---------------------------------------------------------------------------
// NodeNetwork: agg(sum deg=16) -> concat(3x128) -> MLP(384-256-256-128) -> L2n.
// R16: 64-row blocks, two sub-tiles A/B. Tile B's msg stream is issued at the
// top of each of A's MLP stretches and consumed after the next barrier -- the
// compiler's vmcnt(0)-before-s_barrier drain becomes the stream wait, hiding
// A's MLP compute under B's memory time. B's MLP stays exposed.
// LDS 48KB (XA 24K + H 16K + aggB 8K, serial reuse) -> 3 blocks/CU, lb(256,3).
// ---------------------------------------------------------------------------

typedef short short8   __attribute__((ext_vector_type(8)));
typedef short short4_t __attribute__((ext_vector_type(4)));
typedef float f32x4    __attribute__((ext_vector_type(4)));

#define SWZ(row, off) ((off) ^ (((row) & 7) << 4))

__device__ __forceinline__ unsigned short f2bf(float f) {
    unsigned int u = __float_as_uint(f);
    u += 0x7fffu + ((u >> 16) & 1u);   // round-to-nearest-even
    return (unsigned short)(u >> 16);
}

// ---------------------------------------------------------------------------
// Weight prep (unchanged): fp32->bf16, per-lane MFMA B-fragment order.
// ---------------------------------------------------------------------------
__global__ void prep_weights(const float* __restrict__ W1,
                             const float* __restrict__ W2,
                             const float* __restrict__ W3,
                             short* __restrict__ pw1,
                             short* __restrict__ pw2,
                             short* __restrict__ pw3) {
    int idx = blockIdx.x * 256 + threadIdx.x;
    if (idx < 98304) {                       // W1 [384][256]
        int j = idx & 7, l = (idx >> 3) & 63, g = idx >> 9;
        int ks = g % 12, tn = g / 12;
        int n = tn * 16 + (l & 15);
        int k = ks * 32 + ((l >> 4) << 3) + j;
        pw1[idx] = (short)f2bf(W1[k * 256 + n]);
    } else if (idx < 98304 + 65536) {        // W2 [256][256]
        int e = idx - 98304;
        int j = e & 7, l = (e >> 3) & 63, g = e >> 9;
        int ks = g & 7, tn = g >> 3;
        int n = tn * 16 + (l & 15);
        int k = ks * 32 + ((l >> 4) << 3) + j;
        pw2[e] = (short)f2bf(W2[k * 256 + n]);
    } else if (idx < 98304 + 65536 + 32768) { // W3 [256][128]
        int e = idx - 98304 - 65536;
        int j = e & 7, l = (e >> 3) & 63, g = e >> 9;
        int ks = g & 7, tn = g >> 3;
        int n = tn * 16 + (l & 15);
        int k = ks * 32 + ((l >> 4) << 3) + j;
        pw3[e] = (short)f2bf(W3[k * 128 + n]);
    }
}

// ---------------------------------------------------------------------------
__global__ __launch_bounds__(256, 3) void node_net_fused2(
    const float* __restrict__ msg,
    const float* __restrict__ feat,
    const float* __restrict__ glob,
    const float* __restrict__ b1v,
    const float* __restrict__ b2v,
    const float* __restrict__ b3v,
    const short* __restrict__ pw1,
    const short* __restrict__ pw2,
    const short* __restrict__ pw3,
    float* __restrict__ out,
    int n_rows)
{
    __shared__ char lds[49152];
    char* XA = lds;            // 24K: aggA|featA|globA ; h2 over [0:16K]; fgB over [8K:24K]
    char* H  = lds + 24576;    // 16K: h1 -> out -> h1B -> outB (serial)
    char* AB = lds + 40960;    // 8K : aggB [32][128] bf16 swz

    const int tid  = threadIdx.x;
    const int lane = tid & 63;
    const int w    = tid >> 6;
    const int lr   = lane & 15;
    const int lk   = lane >> 4;
    const long long r0 = (long long)blockIdx.x * 64;   // A rows r0.., B rows r0+32..
    const f32x4 zero4 = {0.f, 0.f, 0.f, 0.f};

    f32x4 fr[4], gr[4];
    f32x4 cA[8], cB[8];        // in-flight B msg pair-chunk

// ---- chunk helpers (pair = rows gA, gA+1 of tile B) ----
#define ISSUE_PAIR(k) {                                                        \
    const long long gA_ = r0 + 32 + 8 * w + 2 * (k);                           \
    const f32x4* base_ = (const f32x4*)msg + gA_ * 512;                        \
    const bool okA_ = gA_ < n_rows, okB_ = (gA_ + 1) < n_rows;                 \
    _Pragma("unroll")                                                          \
    for (int i = 0; i < 8; ++i)                                                \
        cA[i] = okA_ ? __builtin_nontemporal_load(base_ + i * 64 + lane) : zero4; \
    _Pragma("unroll")                                                          \
    for (int i = 0; i < 8; ++i)                                                \
        cB[i] = okB_ ? __builtin_nontemporal_load(base_ + 512 + i * 64 + lane) : zero4; }

#define CONSUME_PAIR(k) {                                                      \
    f32x4 sA_ = ((cA[0]+cA[1])+(cA[2]+cA[3])) + ((cA[4]+cA[5])+(cA[6]+cA[7])); \
    f32x4 sB_ = ((cB[0]+cB[1])+(cB[2]+cB[3])) + ((cB[4]+cB[5])+(cB[6]+cB[7])); \
    _Pragma("unroll")                                                          \
    for (int c = 0; c < 4; ++c) {                                              \
        sA_[c] += __shfl_xor(sA_[c], 32);                                      \
        sB_[c] += __shfl_xor(sB_[c], 32);                                      \
    }                                                                          \
    f32x4 s_ = (lane < 32) ? sA_ : sB_;                                        \
    short4_t s4_;                                                              \
    s4_[0]=(short)f2bf(s_[0]); s4_[1]=(short)f2bf(s_[1]);                      \
    s4_[2]=(short)f2bf(s_[2]); s4_[3]=(short)f2bf(s_[3]);                      \
    const int rb_ = 8 * w + 2 * (k) + (lane >> 5);                             \
    *(short4_t*)(AB + SWZ(rb_, rb_ * 256 + (lane & 31) * 8)) = s4_; }

    // ---- entry: frA/grA NT loads ----
    #pragma unroll
    for (int q = 0; q < 4; ++q) {
        int r = (tid >> 5) + q * 8;
        long long row = r0 + r;
        fr[q] = zero4; gr[q] = zero4;
        if (row < n_rows) {
            fr[q] = __builtin_nontemporal_load((const f32x4*)feat + row * 32 + (tid & 31));
            gr[q] = __builtin_nontemporal_load((const f32x4*)glob + row * 32 + (tid & 31));
        }
    }

    // ---- Phase A: aggregate tile A (R9 exact) -> XA[0:8K] ----
    #pragma unroll 1
    for (int pp = 0; pp < 4; ++pp) {
        const int rA = 8 * w + 2 * pp;
        const long long rowA = r0 + rA;
        const f32x4* base = (const f32x4*)msg + rowA * 512;
        f32x4 tA[8], tB[8];
        const bool okA = rowA < n_rows;
        const bool okB = (rowA + 1) < n_rows;
        #pragma unroll
        for (int i = 0; i < 8; ++i)
            tA[i] = okA ? __builtin_nontemporal_load(base + i * 64 + lane) : zero4;
        #pragma unroll
        for (int i = 0; i < 8; ++i)
            tB[i] = okB ? __builtin_nontemporal_load(base + 512 + i * 64 + lane) : zero4;
        f32x4 sA = ((tA[0]+tA[1])+(tA[2]+tA[3])) + ((tA[4]+tA[5])+(tA[6]+tA[7]));
        f32x4 sB = ((tB[0]+tB[1])+(tB[2]+tB[3])) + ((tB[4]+tB[5])+(tB[6]+tB[7]));
        #pragma unroll
        for (int c = 0; c < 4; ++c) {
            sA[c] += __shfl_xor(sA[c], 32);
            sB[c] += __shfl_xor(sB[c], 32);
        }
        f32x4 s = (lane < 32) ? sA : sB;
        short4_t s4;
        s4[0]=(short)f2bf(s[0]); s4[1]=(short)f2bf(s[1]);
        s4[2]=(short)f2bf(s[2]); s4[3]=(short)f2bf(s[3]);
        const int orow = rA + (lane >> 5);
        *(short4_t*)(XA + SWZ(orow, orow * 256 + (lane & 31) * 8)) = s4;
    }
    // stage frA/grA -> XA[8K:24K]
    #pragma unroll
    for (int q = 0; q < 4; ++q) {
        int r = (tid >> 5) + q * 8;
        short4_t sf, sg;
        sf[0]=(short)f2bf(fr[q][0]); sf[1]=(short)f2bf(fr[q][1]);
        sf[2]=(short)f2bf(fr[q][2]); sf[3]=(short)f2bf(fr[q][3]);
        sg[0]=(short)f2bf(gr[q][0]); sg[1]=(short)f2bf(gr[q][1]);
        sg[2]=(short)f2bf(gr[q][2]); sg[3]=(short)f2bf(gr[q][3]);
        *(short4_t*)(XA + 8192  + SWZ(r, r * 256 + (tid & 31) * 8)) = sf;
        *(short4_t*)(XA + 16384 + SWZ(r, r * 256 + (tid & 31) * 8)) = sg;
    }
    __syncthreads();                                   // sync1

    // ========== s1: issue P0 | GEMM1-A (12 ks) + epi1-A -> H ==========
    ISSUE_PAIR(0)
    f32x4 acc1[2][4];
    #pragma unroll
    for (int ri = 0; ri < 2; ++ri)
        #pragma unroll
        for (int ci = 0; ci < 4; ++ci) acc1[ri][ci] = zero4;
    #pragma unroll
    for (int ks = 0; ks < 12; ++ks) {
        const int p = ks >> 2, s = ks & 3;
        short8 a[2], b[4];
        #pragma unroll
        for (int ri = 0; ri < 2; ++ri) {
            int row = ri * 16 + lr;
            a[ri] = *(const short8*)(XA + p * 8192 + SWZ(row, row * 256 + s * 64 + lk * 16));
        }
        #pragma unroll
        for (int ci = 0; ci < 4; ++ci)
            b[ci] = *(const short8*)(pw1 + ((((w * 4 + ci) * 12 + ks) * 64 + lane) << 3));
        #pragma unroll
        for (int ri = 0; ri < 2; ++ri)
            #pragma unroll
            for (int ci = 0; ci < 4; ++ci)
                acc1[ri][ci] = __builtin_amdgcn_mfma_f32_16x16x32_bf16(
                    a[ri], b[ci], acc1[ri][ci], 0, 0, 0);
    }
    #pragma unroll
    for (int ci = 0; ci < 4; ++ci) {
        int col = w * 64 + ci * 16 + lr;
        float bias = b1v[col];
        #pragma unroll
        for (int ri = 0; ri < 2; ++ri)
            #pragma unroll
            for (int i = 0; i < 4; ++i) {
                int row = ri * 16 + lk * 4 + i;
                float v = fmaxf(acc1[ri][ci][i] + bias, 0.f);
                *(short*)(H + SWZ(row, row * 512 + col * 2)) = (short)f2bf(v);
            }
    }
    __syncthreads();                                   // sync2 (drains P0)

    // ========== s2: consume P0, issue P1 | GEMM2-A + epi2-A -> XA[0:16K] ===
    CONSUME_PAIR(0)
    ISSUE_PAIR(1)
    {
        f32x4 acc2[2][4];
        #pragma unroll
        for (int ri = 0; ri < 2; ++ri)
            #pragma unroll
            for (int ci = 0; ci < 4; ++ci) acc2[ri][ci] = zero4;
        #pragma unroll
        for (int s = 0; s < 8; ++s) {
            short8 a[2], b[4];
            #pragma unroll
            for (int ri = 0; ri < 2; ++ri) {
                int row = ri * 16 + lr;
                a[ri] = *(const short8*)(H + SWZ(row, row * 512 + s * 64 + lk * 16));
            }
            #pragma unroll
            for (int ci = 0; ci < 4; ++ci)
                b[ci] = *(const short8*)(pw2 + ((((w * 4 + ci) * 8 + s) * 64 + lane) << 3));
            #pragma unroll
            for (int ri = 0; ri < 2; ++ri)
                #pragma unroll
                for (int ci = 0; ci < 4; ++ci)
                    acc2[ri][ci] = __builtin_amdgcn_mfma_f32_16x16x32_bf16(
                        a[ri], b[ci], acc2[ri][ci], 0, 0, 0);
        }
        #pragma unroll
        for (int ci = 0; ci < 4; ++ci) {
            int col = w * 64 + ci * 16 + lr;
            float bias = b2v[col];
            #pragma unroll
            for (int ri = 0; ri < 2; ++ri)
                #pragma unroll
                for (int i = 0; i < 4; ++i) {
                    int row = ri * 16 + lk * 4 + i;
                    float v = fmaxf(acc2[ri][ci][i] + bias, 0.f);
                    *(short*)(XA + SWZ(row, row * 512 + col * 2)) = (short)f2bf(v);
                }
        }
    }
    __syncthreads();                                   // sync3 (drains P1)

    // ========== s3: consume P1, issue P2 | GEMM3-A + epi3-A -> H (f32) =====
    CONSUME_PAIR(1)
    ISSUE_PAIR(2)
    {
        f32x4 acc3[2][2];
        #pragma unroll
        for (int ri = 0; ri < 2; ++ri)
            #pragma unroll
            for (int ci = 0; ci < 2; ++ci) acc3[ri][ci] = zero4;
        #pragma unroll
        for (int s = 0; s < 8; ++s) {
            short8 a[2], b[2];
            #pragma unroll
            for (int ri = 0; ri < 2; ++ri) {
                int row = ri * 16 + lr;
                a[ri] = *(const short8*)(XA + SWZ(row, row * 512 + s * 64 + lk * 16));
            }
            #pragma unroll
            for (int ci = 0; ci < 2; ++ci)
                b[ci] = *(const short8*)(pw3 + ((((w * 2 + ci) * 8 + s) * 64 + lane) << 3));
            #pragma unroll
            for (int ri = 0; ri < 2; ++ri)
                #pragma unroll
                for (int ci = 0; ci < 2; ++ci)
                    acc3[ri][ci] = __builtin_amdgcn_mfma_f32_16x16x32_bf16(
                        a[ri], b[ci], acc3[ri][ci], 0, 0, 0);
        }
        #pragma unroll
        for (int ci = 0; ci < 2; ++ci) {
            int col = w * 32 + ci * 16 + lr;
            float bias = b3v[col];
            #pragma unroll
            for (int ri = 0; ri < 2; ++ri)
                #pragma unroll
                for (int i = 0; i < 4; ++i) {
                    int row = ri * 16 + lk * 4 + i;
                    float v = acc3[ri][ci][i] + bias;
                    *(float*)(H + SWZ(row, row * 512 + col * 4)) = v;
                }
        }
    }
    __syncthreads();                                   // sync4 (drains P2)

    // ========== s4: consume P2, issue P3 + frB/grB | norm-A + store-A ======
    CONSUME_PAIR(2)
    ISSUE_PAIR(3)
    #pragma unroll
    for (int q = 0; q < 4; ++q) {
        int r = (tid >> 5) + q * 8;
        long long row = r0 + 32 + r;
        fr[q] = zero4; gr[q] = zero4;
        if (row < n_rows) {
            fr[q] = __builtin_nontemporal_load((const f32x4*)feat + row * 32 + (tid & 31));
            gr[q] = __builtin_nontemporal_load((const f32x4*)glob + row * 32 + (tid & 31));
        }
    }
    #pragma unroll
    for (int pass = 0; pass < 4; ++pass) {
        const int r  = (tid >> 5) + pass * 8;
        const int fl = tid & 31;
        f32x4 v = *(const f32x4*)(H + SWZ(r, r * 512 + fl * 16));
        float ss = v[0]*v[0] + v[1]*v[1] + v[2]*v[2] + v[3]*v[3];
        ss += __shfl_xor(ss, 1, 32);
        ss += __shfl_xor(ss, 2, 32);
        ss += __shfl_xor(ss, 4, 32);
        ss += __shfl_xor(ss, 8, 32);
        ss += __shfl_xor(ss, 16, 32);
        float inv = 1.f / (sqrtf(ss) + 1e-8f);
        long long row = r0 + r;
        if (row < n_rows) {
            f32x4 o = v * inv;
            __builtin_nontemporal_store(o, (f32x4*)out + row * 32 + fl);
        }
    }
    __syncthreads();                                   // sync5 (drains P3 + fgB)

    // ========== s5: consume P3, stage fgB -> XA[8K:24K] ====================
    CONSUME_PAIR(3)
    #pragma unroll
    for (int q = 0; q < 4; ++q) {
        int r = (tid >> 5) + q * 8;
        short4_t sf, sg;
        sf[0]=(short)f2bf(fr[q][0]); sf[1]=(short)f2bf(fr[q][1]);
        sf[2]=(short)f2bf(fr[q][2]); sf[3]=(short)f2bf(fr[q][3]);
        sg[0]=(short)f2bf(gr[q][0]); sg[1]=(short)f2bf(gr[q][1]);
        sg[2]=(short)f2bf(gr[q][2]); sg[3]=(short)f2bf(gr[q][3]);
        *(short4_t*)(XA + 8192  + SWZ(r, r * 256 + (tid & 31) * 8)) = sf;
        *(short4_t*)(XA + 16384 + SWZ(r, r * 256 + (tid & 31) * 8)) = sg;
    }
    __syncthreads();                                   // sync6

    // ========== s6: GEMM1-B (aggB + fgB) + epi1-B -> H =====================
    #pragma unroll
    for (int ri = 0; ri < 2; ++ri)
        #pragma unroll
        for (int ci = 0; ci < 4; ++ci) acc1[ri][ci] = zero4;
    #pragma unroll
    for (int ks = 0; ks < 12; ++ks) {
        const int p = ks >> 2, s = ks & 3;
        const char* abase = (p == 0) ? AB : (XA + p * 8192);
        short8 a[2], b[4];
        #pragma unroll
        for (int ri = 0; ri < 2; ++ri) {
            int row = ri * 16 + lr;
            a[ri] = *(const short8*)(abase + SWZ(row, row * 256 + s * 64 + lk * 16));
        }
        #pragma unroll
        for (int ci = 0; ci < 4; ++ci)
            b[ci] = *(const short8*)(pw1 + ((((w * 4 + ci) * 12 + ks) * 64 + lane) << 3));
        #pragma unroll
        for (int ri = 0; ri < 2; ++ri)
            #pragma unroll
            for (int ci = 0; ci < 4; ++ci)
                acc1[ri][ci] = __builtin_amdgcn_mfma_f32_16x16x32_bf16(
                    a[ri], b[ci], acc1[ri][ci], 0, 0, 0);
    }
    #pragma unroll
    for (int ci = 0; ci < 4; ++ci) {
        int col = w * 64 + ci * 16 + lr;
        float bias = b1v[col];
        #pragma unroll
        for (int ri = 0; ri < 2; ++ri)
            #pragma unroll
            for (int i = 0; i < 4; ++i) {
                int row = ri * 16 + lk * 4 + i;
                float v = fmaxf(acc1[ri][ci][i] + bias, 0.f);
                *(short*)(H + SWZ(row, row * 512 + col * 2)) = (short)f2bf(v);
            }
    }
    __syncthreads();                                   // sync7

    // ========== s7: GEMM2-B + epi2-B -> XA[0:16K] ==========================
    {
        f32x4 acc2[2][4];
        #pragma unroll
        for (int ri = 0; ri < 2; ++ri)
            #pragma unroll
            for (int ci = 0; ci < 4; ++ci) acc2[ri][ci] = zero4;
        #pragma unroll
        for (int s = 0; s < 8; ++s) {
            short8 a[2], b[4];
            #pragma unroll
            for (int ri = 0; ri < 2; ++ri) {
                int row = ri * 16 + lr;
                a[ri] = *(const short8*)(H + SWZ(row, row * 512 + s * 64 + lk * 16));
            }
            #pragma unroll
            for (int ci = 0; ci < 4; ++ci)
                b[ci] = *(const short8*)(pw2 + ((((w * 4 + ci) * 8 + s) * 64 + lane) << 3));
            #pragma unroll
            for (int ri = 0; ri < 2; ++ri)
                #pragma unroll
                for (int ci = 0; ci < 4; ++ci)
                    acc2[ri][ci] = __builtin_amdgcn_mfma_f32_16x16x32_bf16(
                        a[ri], b[ci], acc2[ri][ci], 0, 0, 0);
        }
        #pragma unroll
        for (int ci = 0; ci < 4; ++ci) {
            int col = w * 64 + ci * 16 + lr;
            float bias = b2v[col];
            #pragma unroll
            for (int ri = 0; ri < 2; ++ri)
                #pragma unroll
                for (int i = 0; i < 4; ++i) {
                    int row = ri * 16 + lk * 4 + i;
                    float v = fmaxf(acc2[ri][ci][i] + bias, 0.f);
                    *(short*)(XA + SWZ(row, row * 512 + col * 2)) = (short)f2bf(v);
                }
        }
    }
    __syncthreads();                                   // sync8

    // ========== s8: GEMM3-B + epi3-B -> H (f32) ============================
    {
        f32x4 acc3[2][2];
        #pragma unroll
        for (int ri = 0; ri < 2; ++ri)
            #pragma unroll
            for (int ci = 0; ci < 2; ++ci) acc3[ri][ci] = zero4;
        #pragma unroll
        for (int s = 0; s < 8; ++s) {
            short8 a[2], b[2];
            #pragma unroll
            for (int ri = 0; ri < 2; ++ri) {
                int row = ri * 16 + lr;
                a[ri] = *(const short8*)(XA + SWZ(row, row * 512 + s * 64 + lk * 16));
            }
            #pragma unroll
            for (int ci = 0; ci < 2; ++ci)
                b[ci] = *(const short8*)(pw3 + ((((w * 2 + ci) * 8 + s) * 64 + lane) << 3));
            #pragma unroll
            for (int ri = 0; ri < 2; ++ri)
                #pragma unroll
                for (int ci = 0; ci < 2; ++ci)
                    acc3[ri][ci] = __builtin_amdgcn_mfma_f32_16x16x32_bf16(
                        a[ri], b[ci], acc3[ri][ci], 0, 0, 0);
        }
        #pragma unroll
        for (int ci = 0; ci < 2; ++ci) {
            int col = w * 32 + ci * 16 + lr;
            float bias = b3v[col];
            #pragma unroll
            for (int ri = 0; ri < 2; ++ri)
                #pragma unroll
                for (int i = 0; i < 4; ++i) {
                    int row = ri * 16 + lk * 4 + i;
                    float v = acc3[ri][ci][i] + bias;
                    *(float*)(H + SWZ(row, row * 512 + col * 4)) = v;
                }
        }
    }
    __syncthreads();                                   // sync9

    // ========== s9: norm-B + store-B ======================================
    #pragma unroll
    for (int pass = 0; pass < 4; ++pass) {
        const int r  = (tid >> 5) + pass * 8;
        const int fl = tid & 31;
        f32x4 v = *(const f32x4*)(H + SWZ(r, r * 512 + fl * 16));
        float ss = v[0]*v[0] + v[1]*v[1] + v[2]*v[2] + v[3]*v[3];
        ss += __shfl_xor(ss, 1, 32);
        ss += __shfl_xor(ss, 2, 32);
        ss += __shfl_xor(ss, 4, 32);
        ss += __shfl_xor(ss, 8, 32);
        ss += __shfl_xor(ss, 16, 32);
        float inv = 1.f / (sqrtf(ss) + 1e-8f);
        long long row = r0 + 32 + r;
        if (row < n_rows) {
            f32x4 o = v * inv;
            __builtin_nontemporal_store(o, (f32x4*)out + row * 32 + fl);
        }
    }
#undef ISSUE_PAIR
#undef CONSUME_PAIR
}

// ---------------------------------------------------------------------------
extern "C" void kernel_launch(void* const* d_in, const int* in_sizes, int n_in,
                              void* d_out, int out_size, void* d_ws, size_t ws_size,
                              hipStream_t stream) {
    const float* msg  = (const float*)d_in[0];
    const float* feat = (const float*)d_in[1];
    const float* glob = (const float*)d_in[2];
    const float* W1   = (const float*)d_in[3];
    const float* b1   = (const float*)d_in[4];
    const float* W2   = (const float*)d_in[5];
    const float* b2   = (const float*)d_in[6];
    const float* W3   = (const float*)d_in[7];
    const float* b3   = (const float*)d_in[8];
    float* out = (float*)d_out;

    const int n_rows = in_sizes[1] / 128;   // features is [N,128]

    short* pw1 = (short*)d_ws;              // 98304 bf16
    short* pw2 = pw1 + 98304;               // 65536 bf16
    short* pw3 = pw2 + 65536;               // 32768 bf16

    hipLaunchKernelGGL(prep_weights, dim3(768), dim3(256), 0, stream,
                       W1, W2, W3, pw1, pw2, pw3);

    const int nblocks = (n_rows + 63) / 64;  // 64 rows (2 sub-tiles) per block
    hipLaunchKernelGGL(node_net_fused2, dim3(nblocks), dim3(256), 0, stream,
                       msg, feat, glob, b1, b2, b3, pw1, pw2, pw3, out, n_rows);
}

// Round 17
// 1121.534 us; speedup vs baseline: 1.6154x; 1.6154x over previous
//
#include <hip/hip_runtime.h>

// ---------------------------------------------------------------------------
// NodeNetwork: agg(sum over deg=16) -> concat(3x128) -> MLP(384-256-256-128)
//              -> row L2 normalize.  N=500000 rows.
// R17: R9 (best, 1080us) + ONE-TIME slot-aligned stagger. The fused kernel's
// 4 slots/CU convoy (measured duty loss 27% vs 0.2% for independent phases);
// hardware refill preserves phases, so ONLY the first machine-filling
// generation (blockIdx<1024) needs offsetting: delay ((bid>>8)&3) x ~T/4
// (under round-robin dispatch, a CU's 4 first-gen blocks are b,b+256,b+512,
// b+768 -> offsets {0,1,2,3}). Later blocks inherit desynced slot phases
// free. Unlike R13 (per-block delay every rotation), cost is ~1-2us total.
// Kernel body byte-identical to R9.
// ---------------------------------------------------------------------------

typedef short short8   __attribute__((ext_vector_type(8)));
typedef short short4_t __attribute__((ext_vector_type(4)));
typedef float f32x4    __attribute__((ext_vector_type(4)));

#define SWZ(row, off) ((off) ^ (((row) & 7) << 4))

__device__ __forceinline__ unsigned short f2bf(float f) {
    unsigned int u = __float_as_uint(f);
    u += 0x7fffu + ((u >> 16) & 1u);   // round-to-nearest-even
    return (unsigned short)(u >> 16);
}

// ---------------------------------------------------------------------------
// Weight prep (unchanged): fp32->bf16, per-lane MFMA B-fragment order:
//   pw[((tn*KS + ks)*64 + lane)*8 + j] = bf16( W[k][n] )
//   n = tn*16 + (lane&15), k = ks*32 + (lane>>4)*8 + j
// ---------------------------------------------------------------------------
__global__ void prep_weights(const float* __restrict__ W1,
                             const float* __restrict__ W2,
                             const float* __restrict__ W3,
                             short* __restrict__ pw1,
                             short* __restrict__ pw2,
                             short* __restrict__ pw3) {
    int idx = blockIdx.x * 256 + threadIdx.x;
    if (idx < 98304) {                       // W1 [384][256]
        int j = idx & 7, l = (idx >> 3) & 63, g = idx >> 9;
        int ks = g % 12, tn = g / 12;
        int n = tn * 16 + (l & 15);
        int k = ks * 32 + ((l >> 4) << 3) + j;
        pw1[idx] = (short)f2bf(W1[k * 256 + n]);
    } else if (idx < 98304 + 65536) {        // W2 [256][256]
        int e = idx - 98304;
        int j = e & 7, l = (e >> 3) & 63, g = e >> 9;
        int ks = g & 7, tn = g >> 3;
        int n = tn * 16 + (l & 15);
        int k = ks * 32 + ((l >> 4) << 3) + j;
        pw2[e] = (short)f2bf(W2[k * 256 + n]);
    } else if (idx < 98304 + 65536 + 32768) { // W3 [256][128]
        int e = idx - 98304 - 65536;
        int j = e & 7, l = (e >> 3) & 63, g = e >> 9;
        int ks = g & 7, tn = g >> 3;
        int n = tn * 16 + (l & 15);
        int k = ks * 32 + ((l >> 4) << 3) + j;
        pw3[e] = (short)f2bf(W3[k * 128 + n]);
    }
}

// ---------------------------------------------------------------------------
// Fused kernel: 32 rows/block, 256 threads (4 waves), 32KB LDS, 4 blocks/CU.
// Body identical to R9; one-time first-generation stagger at entry.
// ---------------------------------------------------------------------------
__global__ __launch_bounds__(256, 4) void node_net_fused(
    const float* __restrict__ msg,
    const float* __restrict__ feat,
    const float* __restrict__ glob,
    const float* __restrict__ b1v,
    const float* __restrict__ b2v,
    const float* __restrict__ b3v,
    const short* __restrict__ pw1,
    const short* __restrict__ pw2,
    const short* __restrict__ pw3,
    float* __restrict__ out,
    int n_rows)
{
    __shared__ char lds[32768];
    char* regA = lds;            // 16KB
    char* regB = lds + 16384;    // 16KB

    // ---- one-time slot-aligned stagger (first machine-filling gen only) ----
    if (blockIdx.x < 1024) {
        const int q = (blockIdx.x >> 8) & 3;      // slot quadrant 0..3
        const int spin = q * 3000;                // ~17us per quadrant (T/4)
        for (int i = 0; i < spin; ++i)
            asm volatile("s_nop 7" ::: "memory");
    }

    const int tid  = threadIdx.x;
    const int lane = tid & 63;
    const int w    = tid >> 6;
    const int lr   = lane & 15;
    const int lk   = lane >> 4;
    const long long r0 = (long long)blockIdx.x * 32;

    const f32x4 zero4 = {0.f, 0.f, 0.f, 0.f};

    // ---- issue feat/glob NT loads first (consumed after sync1/sync2) ----
    f32x4 fr[4], gr[4];
    #pragma unroll
    for (int q = 0; q < 4; ++q) {
        int r = (tid >> 5) + q * 8;
        long long row = r0 + r;
        fr[q] = zero4; gr[q] = zero4;
        if (row < n_rows) {
            fr[q] = __builtin_nontemporal_load((const f32x4*)feat + row * 32 + (tid & 31));
            gr[q] = __builtin_nontemporal_load((const f32x4*)glob + row * 32 + (tid & 31));
        }
    }

    // ---- Phase A: msg aggregation -> regB[0:8K] ----
    // Wave w owns rows [8w, 8w+8) as 4 pairs; per pair 16 x 1KB NT loads.
    #pragma unroll 1
    for (int pp = 0; pp < 4; ++pp) {
        const int rA = 8 * w + 2 * pp;          // tile-local row (pair base)
        const long long rowA = r0 + rA;
        const f32x4* base = (const f32x4*)msg + rowA * 512;  // 512 f32x4/row
        f32x4 tA[8], tB[8];
        const bool okA = rowA < n_rows;
        const bool okB = (rowA + 1) < n_rows;
        #pragma unroll
        for (int i = 0; i < 8; ++i)
            tA[i] = okA ? __builtin_nontemporal_load(base + i * 64 + lane) : zero4;
        #pragma unroll
        for (int i = 0; i < 8; ++i)
            tB[i] = okB ? __builtin_nontemporal_load(base + 512 + i * 64 + lane) : zero4;
        f32x4 sA = ((tA[0]+tA[1])+(tA[2]+tA[3])) + ((tA[4]+tA[5])+(tA[6]+tA[7]));
        f32x4 sB = ((tB[0]+tB[1])+(tB[2]+tB[3])) + ((tB[4]+tB[5])+(tB[6]+tB[7]));
        #pragma unroll
        for (int c = 0; c < 4; ++c) {
            sA[c] += __shfl_xor(sA[c], 32);
            sB[c] += __shfl_xor(sB[c], 32);
        }
        f32x4 s = (lane < 32) ? sA : sB;
        short4_t s4;
        s4[0] = (short)f2bf(s[0]); s4[1] = (short)f2bf(s[1]);
        s4[2] = (short)f2bf(s[2]); s4[3] = (short)f2bf(s[3]);
        const int orow = rA + (lane >> 5);
        *(short4_t*)(regB + SWZ(orow, orow * 256 + (lane & 31) * 8)) = s4;
    }
    __syncthreads();                                   // sync1

    // ---- stage feat regs -> regA[0:8K] (consumed after sync2) ----
    #pragma unroll
    for (int q = 0; q < 4; ++q) {
        int r = (tid >> 5) + q * 8;
        short4_t s4;
        s4[0] = (short)f2bf(fr[q][0]); s4[1] = (short)f2bf(fr[q][1]);
        s4[2] = (short)f2bf(fr[q][2]); s4[3] = (short)f2bf(fr[q][3]);
        *(short4_t*)(regA + SWZ(r, r * 256 + (tid & 31) * 8)) = s4;
    }

    f32x4 acc1[2][4];
    #pragma unroll
    for (int ri = 0; ri < 2; ++ri)
        #pragma unroll
        for (int ci = 0; ci < 4; ++ci) acc1[ri][ci] = zero4;

    // ---- GEMM1 part 0 (agg), ks = 0..3, reads regB[0:8K] ----
    #pragma unroll
    for (int s = 0; s < 4; ++s) {
        short8 a[2], b[4];
        #pragma unroll
        for (int ri = 0; ri < 2; ++ri) {
            int row = ri * 16 + lr;
            a[ri] = *(const short8*)(regB + SWZ(row, row * 256 + s * 64 + lk * 16));
        }
        #pragma unroll
        for (int ci = 0; ci < 4; ++ci) {
            int tn = w * 4 + ci;
            b[ci] = *(const short8*)(pw1 + (((tn * 12 + s) * 64 + lane) << 3));
        }
        #pragma unroll
        for (int ri = 0; ri < 2; ++ri)
            #pragma unroll
            for (int ci = 0; ci < 4; ++ci)
                acc1[ri][ci] = __builtin_amdgcn_mfma_f32_16x16x32_bf16(
                    a[ri], b[ci], acc1[ri][ci], 0, 0, 0);
    }
    __syncthreads();                                   // sync2

    // ---- stage glob regs -> regB[8K:16K] (consumed after sync3) ----
    #pragma unroll
    for (int q = 0; q < 4; ++q) {
        int r = (tid >> 5) + q * 8;
        short4_t s4;
        s4[0] = (short)f2bf(gr[q][0]); s4[1] = (short)f2bf(gr[q][1]);
        s4[2] = (short)f2bf(gr[q][2]); s4[3] = (short)f2bf(gr[q][3]);
        *(short4_t*)(regB + 8192 + SWZ(r, r * 256 + (tid & 31) * 8)) = s4;
    }

    // ---- GEMM1 part 1 (feat), ks = 4..7, reads regA[0:8K] ----
    #pragma unroll
    for (int s = 0; s < 4; ++s) {
        short8 a[2], b[4];
        #pragma unroll
        for (int ri = 0; ri < 2; ++ri) {
            int row = ri * 16 + lr;
            a[ri] = *(const short8*)(regA + SWZ(row, row * 256 + s * 64 + lk * 16));
        }
        #pragma unroll
        for (int ci = 0; ci < 4; ++ci) {
            int tn = w * 4 + ci;
            b[ci] = *(const short8*)(pw1 + (((tn * 12 + 4 + s) * 64 + lane) << 3));
        }
        #pragma unroll
        for (int ri = 0; ri < 2; ++ri)
            #pragma unroll
            for (int ci = 0; ci < 4; ++ci)
                acc1[ri][ci] = __builtin_amdgcn_mfma_f32_16x16x32_bf16(
                    a[ri], b[ci], acc1[ri][ci], 0, 0, 0);
    }
    __syncthreads();                                   // sync3

    // ---- GEMM1 part 2 (glob), ks = 8..11, reads regB[8K:16K] ----
    #pragma unroll
    for (int s = 0; s < 4; ++s) {
        short8 a[2], b[4];
        #pragma unroll
        for (int ri = 0; ri < 2; ++ri) {
            int row = ri * 16 + lr;
            a[ri] = *(const short8*)(regB + 8192 + SWZ(row, row * 256 + s * 64 + lk * 16));
        }
        #pragma unroll
        for (int ci = 0; ci < 4; ++ci) {
            int tn = w * 4 + ci;
            b[ci] = *(const short8*)(pw1 + (((tn * 12 + 8 + s) * 64 + lane) << 3));
        }
        #pragma unroll
        for (int ri = 0; ri < 2; ++ri)
            #pragma unroll
            for (int ci = 0; ci < 4; ++ci)
                acc1[ri][ci] = __builtin_amdgcn_mfma_f32_16x16x32_bf16(
                    a[ri], b[ci], acc1[ri][ci], 0, 0, 0);
    }

    // ---- epilogue 1: +b1, ReLU, bf16 -> h1 in regA ----
    #pragma unroll
    for (int ci = 0; ci < 4; ++ci) {
        int col = w * 64 + ci * 16 + lr;
        float bias = b1v[col];
        #pragma unroll
        for (int ri = 0; ri < 2; ++ri)
            #pragma unroll
            for (int i = 0; i < 4; ++i) {
                int row = ri * 16 + lk * 4 + i;
                float v = fmaxf(acc1[ri][ci][i] + bias, 0.f);
                *(short*)(regA + SWZ(row, row * 512 + col * 2)) = (short)f2bf(v);
            }
    }
    __syncthreads();                                   // sync4

    // ---- GEMM2: h1 @ W2 (reads regA) ----
    f32x4 acc2[2][4];
    #pragma unroll
    for (int ri = 0; ri < 2; ++ri)
        #pragma unroll
        for (int ci = 0; ci < 4; ++ci) acc2[ri][ci] = zero4;

    #pragma unroll
    for (int s = 0; s < 8; ++s) {
        short8 a[2], b[4];
        #pragma unroll
        for (int ri = 0; ri < 2; ++ri) {
            int row = ri * 16 + lr;
            a[ri] = *(const short8*)(regA + SWZ(row, row * 512 + s * 64 + lk * 16));
        }
        #pragma unroll
        for (int ci = 0; ci < 4; ++ci) {
            int tn = w * 4 + ci;
            b[ci] = *(const short8*)(pw2 + (((tn * 8 + s) * 64 + lane) << 3));
        }
        #pragma unroll
        for (int ri = 0; ri < 2; ++ri)
            #pragma unroll
            for (int ci = 0; ci < 4; ++ci)
                acc2[ri][ci] = __builtin_amdgcn_mfma_f32_16x16x32_bf16(
                    a[ri], b[ci], acc2[ri][ci], 0, 0, 0);
    }

    // ---- epilogue 2: +b2, ReLU, bf16 -> h2 in regB ----
    #pragma unroll
    for (int ci = 0; ci < 4; ++ci) {
        int col = w * 64 + ci * 16 + lr;
        float bias = b2v[col];
        #pragma unroll
        for (int ri = 0; ri < 2; ++ri)
            #pragma unroll
            for (int i = 0; i < 4; ++i) {
                int row = ri * 16 + lk * 4 + i;
                float v = fmaxf(acc2[ri][ci][i] + bias, 0.f);
                *(short*)(regB + SWZ(row, row * 512 + col * 2)) = (short)f2bf(v);
            }
    }
    __syncthreads();                                   // sync5

    // ---- GEMM3: h2 @ W3 (reads regB) ----
    f32x4 acc3[2][2];
    #pragma unroll
    for (int ri = 0; ri < 2; ++ri)
        #pragma unroll
        for (int ci = 0; ci < 2; ++ci) acc3[ri][ci] = zero4;

    #pragma unroll
    for (int s = 0; s < 8; ++s) {
        short8 a[2], b[2];
        #pragma unroll
        for (int ri = 0; ri < 2; ++ri) {
            int row = ri * 16 + lr;
            a[ri] = *(const short8*)(regB + SWZ(row, row * 512 + s * 64 + lk * 16));
        }
        #pragma unroll
        for (int ci = 0; ci < 2; ++ci) {
            int tn = w * 2 + ci;
            b[ci] = *(const short8*)(pw3 + (((tn * 8 + s) * 64 + lane) << 3));
        }
        #pragma unroll
        for (int ri = 0; ri < 2; ++ri)
            #pragma unroll
            for (int ci = 0; ci < 2; ++ci)
                acc3[ri][ci] = __builtin_amdgcn_mfma_f32_16x16x32_bf16(
                    a[ri], b[ci], acc3[ri][ci], 0, 0, 0);
    }

    // ---- epilogue 3: +b3, f32 -> out tile in regA ----
    #pragma unroll
    for (int ci = 0; ci < 2; ++ci) {
        int col = w * 32 + ci * 16 + lr;
        float bias = b3v[col];
        #pragma unroll
        for (int ri = 0; ri < 2; ++ri)
            #pragma unroll
            for (int i = 0; i < 4; ++i) {
                int row = ri * 16 + lk * 4 + i;
                float v = acc3[ri][ci][i] + bias;
                *(float*)(regA + SWZ(row, row * 512 + col * 4)) = v;
            }
    }
    __syncthreads();                                   // sync6

    // ---- row-wise L2 normalize + coalesced NT store ----
    #pragma unroll
    for (int pass = 0; pass < 4; ++pass) {
        const int r  = (tid >> 5) + pass * 8;
        const int fl = tid & 31;
        f32x4 v = *(const f32x4*)(regA + SWZ(r, r * 512 + fl * 16));
        float ss = v[0]*v[0] + v[1]*v[1] + v[2]*v[2] + v[3]*v[3];
        ss += __shfl_xor(ss, 1, 32);
        ss += __shfl_xor(ss, 2, 32);
        ss += __shfl_xor(ss, 4, 32);
        ss += __shfl_xor(ss, 8, 32);
        ss += __shfl_xor(ss, 16, 32);
        float inv = 1.f / (sqrtf(ss) + 1e-8f);
        long long row = r0 + r;
        if (row < n_rows) {
            f32x4 o = v * inv;
            __builtin_nontemporal_store(o, (f32x4*)out + row * 32 + fl);
        }
    }
}

// ---------------------------------------------------------------------------
extern "C" void kernel_launch(void* const* d_in, const int* in_sizes, int n_in,
                              void* d_out, int out_size, void* d_ws, size_t ws_size,
                              hipStream_t stream) {
    const float* msg  = (const float*)d_in[0];
    const float* feat = (const float*)d_in[1];
    const float* glob = (const float*)d_in[2];
    const float* W1   = (const float*)d_in[3];
    const float* b1   = (const float*)d_in[4];
    const float* W2   = (const float*)d_in[5];
    const float* b2   = (const float*)d_in[6];
    const float* W3   = (const float*)d_in[7];
    const float* b3   = (const float*)d_in[8];
    float* out = (float*)d_out;

    const int n_rows = in_sizes[1] / 128;   // features is [N,128]

    short* pw1 = (short*)d_ws;              // 98304 bf16
    short* pw2 = pw1 + 98304;               // 65536 bf16
    short* pw3 = pw2 + 65536;               // 32768 bf16

    hipLaunchKernelGGL(prep_weights, dim3(768), dim3(256), 0, stream,
                       W1, W2, W3, pw1, pw2, pw3);

    const int nblocks = (n_rows + 31) / 32;
    hipLaunchKernelGGL(node_net_fused, dim3(nblocks), dim3(256), 0, stream,
                       msg, feat, glob, b1, b2, b3, pw1, pw2, pw3, out, n_rows);
}